// Round 9
// baseline (1115.198 us; speedup 1.0000x reference)
//
#include <hip/hip_runtime.h>
#include <hip/hip_bf16.h>
#include <hip/hip_cooperative_groups.h>
#include <math.h>

namespace cg = cooperative_groups;

#define N_NODES   15000
#define N_EDGES   60000
#define EVOCAB    54
#define NODE_INDIM 64
#define EDGE_INDIM 32
#define H  32
#define EH 64
#define N_BOND 4

// setup task ranges — every boundary is 64-aligned so no wave straddles
#define TASK_VOCAB (EVOCAB * 1024)                  // 55296  (= 864*64)
#define TASK_PROJ  (N_NODES * H)                    // 480000 (= 7500*64)
#define TASK_PACK  (3 * H * H)                      // 3072   (= 48*64)
#define TASK_ZERO  ((N_NODES * H + N_NODES) / 4)    // 123750 float4 (agg+sm contig)
#define TA (TASK_VOCAB + TASK_PROJ + TASK_PACK + TASK_ZERO)   // 662118

struct Params {
    const int *node_ids, *edge_ids, *src, *dst;
    const float *node_table, *edge_table, *proj_W, *proj_b, *attn_w;
    const float *e1_W1, *e1_b1, *e1_W2, *e1_b2;
    const float *e2_W1, *e2_b1, *e2_W2, *e2_b2;
    const float *gWih, *gWhh, *gbih, *gbhh;
    float *Wq;     // packed: Wq[v*1024 + c*128 + o*4 + u] = W_v[4c+u][o]
    float *h;      // [N][32]
    float *ps, *pd;// per-node attention dots
    float4 *Wpk4;  // GRU packed transposed
    float2 *Wpk2;
    float *agg;    // [N][32], sm contiguous after
    float *sm;     // [N]
    float *out;
};

// =========================== shared phase bodies ===========================
__device__ __forceinline__ void phase_setup(const Params& p, int t) {
    if (t < TASK_VOCAB) {
        int v = t >> 10, f = t & 1023, l = t & 63;   // v wave-uniform
        const float* W1 = (v < N_BOND) ? p.e1_W1 : p.e2_W1;
        const float* b1 = (v < N_BOND) ? p.e1_b1 : p.e2_b1;
        const float* W2 = (v < N_BOND) ? p.e1_W2 : p.e2_W2;
        const float* b2 = (v < N_BOND) ? p.e1_b2 : p.e2_b2;
        const float4* ef4 = (const float4*)(p.edge_table + v * EDGE_INDIM);
        const float4* w1r = (const float4*)(W1 + l * EDGE_INDIM);
        float z = b1[l];                              // lane l owns z[l]
        #pragma unroll 4
        for (int c = 0; c < 8; ++c) {
            float4 e4 = ef4[c], w4 = w1r[c];
            z += e4.x * w4.x + e4.y * w4.y + e4.z * w4.z + e4.w * w4.w;
        }
        z = fmaxf(z, 0.f);
        const float4* w2r = (const float4*)(W2 + f * EH);
        float y = b2[f];
        #pragma unroll 4
        for (int c = 0; c < 16; ++c) {
            float4 w4 = w2r[c];
            y += __shfl(z, 4 * c,     64) * w4.x;
            y += __shfl(z, 4 * c + 1, 64) * w4.y;
            y += __shfl(z, 4 * c + 2, 64) * w4.z;
            y += __shfl(z, 4 * c + 3, 64) * w4.w;
        }
        int i = f >> 5, o = f & 31;                   // f = i*32 + o
        p.Wq[v * 1024 + (i >> 2) * 128 + o * 4 + (i & 3)] = y;
    } else if (t < TASK_VOCAB + TASK_PROJ) {
        int q = t - TASK_VOCAB;
        int n = q >> 5, o = q & 31;
        int gid = p.node_ids[n];
        const float4* nf4 = (const float4*)(p.node_table + (size_t)gid * NODE_INDIM);
        const float4* wr4 = (const float4*)(p.proj_W + o * NODE_INDIM);
        float acc = p.proj_b[o];
        #pragma unroll 4
        for (int c = 0; c < 16; ++c) {
            float4 a = nf4[c], w = wr4[c];
            acc += a.x * w.x + a.y * w.y + a.z * w.z + a.w * w.w;
        }
        acc = fmaxf(acc, 0.f);
        p.h[q] = acc;
        float v0 = acc * p.attn_w[o], v1 = acc * p.attn_w[32 + o];
        #pragma unroll
        for (int m = 16; m > 0; m >>= 1) {
            v0 += __shfl_xor(v0, m, 32);
            v1 += __shfl_xor(v1, m, 32);
        }
        if (o == 0) { p.ps[n] = v0; p.pd[n] = v1; }
    } else if (t < TASK_VOCAB + TASK_PROJ + TASK_PACK) {
        int q = t - TASK_VOCAB - TASK_PROJ;           // q = j*32 + o
        int j = q >> 5, o = q & 31;
        p.Wpk4[q] = make_float4(p.gWih[o * 32 + j], p.gWih[(32 + o) * 32 + j],
                                p.gWih[(64 + o) * 32 + j], p.gWhh[o * 32 + j]);
        p.Wpk2[q] = make_float2(p.gWhh[(32 + o) * 32 + j], p.gWhh[(64 + o) * 32 + j]);
    } else {
        int q = t - TASK_VOCAB - TASK_PROJ - TASK_PACK;
        ((float4*)p.agg)[q] = make_float4(0.f, 0.f, 0.f, 0.f);  // agg+sm contig
    }
}

__device__ __forceinline__ void phase_edge(const Params& p, int t) {
    int e = t >> 5, o = t & 31;
    int s = p.src[e], d = p.dst[e], v = p.edge_ids[e];
    float a = p.ps[s] + p.pd[d];
    a = (a > 0.f) ? a : 0.01f * a;                    // leaky_relu 0.01
    float ex = __expf(a);
    const float4* hrow = (const float4*)(p.h + s * 32);        // group bcast
    const float4* W4   = (const float4*)(p.Wq + v * 1024) + o; // coalesced
    float y = 0.f;
    #pragma unroll
    for (int c = 0; c < 8; ++c) {
        float4 h4 = hrow[c];
        float4 w4 = W4[c * 32];                       // W[4c..4c+3][o]
        y += h4.x * w4.x + h4.y * w4.y + h4.z * w4.z + h4.w * w4.w;
    }
    atomicAdd(&p.agg[d * 32 + o], ex * y);
    if (o == 0) atomicAdd(&p.sm[d], ex);
}

__device__ __forceinline__ void phase_gru(const Params& p, int t, int g,
                                          float lm[8][32], float lh[8][32],
                                          float* __restrict__ hout) {
    int n = t >> 5, o = t & 31;
    float den = p.sm[n];
    float m  = (den > 0.f) ? fmaxf(p.agg[t] / den, 0.f) : 0.f;
    float hv = p.h[t];
    lm[g][o] = m;
    lh[g][o] = hv;                                    // same-wave: no barrier
    float gir = 0.f, giz = 0.f, gin = 0.f, ghr = 0.f, ghz = 0.f, ghn = 0.f;
    #pragma unroll
    for (int c = 0; c < 8; ++c) {
        float4 m4 = ((const float4*)lm[g])[c];
        float4 h4 = ((const float4*)lh[g])[c];
        #pragma unroll
        for (int u = 0; u < 4; ++u) {
            int j = 4 * c + u;
            float mj = (u == 0) ? m4.x : (u == 1) ? m4.y : (u == 2) ? m4.z : m4.w;
            float hj = (u == 0) ? h4.x : (u == 1) ? h4.y : (u == 2) ? h4.z : h4.w;
            float4 a4 = p.Wpk4[j * 32 + o];
            float2 b2 = p.Wpk2[j * 32 + o];
            gir += mj * a4.x;  giz += mj * a4.y;  gin += mj * a4.z;
            ghr += hj * a4.w;  ghz += hj * b2.x;  ghn += hj * b2.y;
        }
    }
    float r  = 1.f / (1.f + __expf(-(gir + p.gbih[o]      + ghr + p.gbhh[o])));
    float z  = 1.f / (1.f + __expf(-(giz + p.gbih[32 + o] + ghz + p.gbhh[32 + o])));
    float nn = tanhf(gin + p.gbih[64 + o] + r * (ghn + p.gbhh[64 + o]));
    float hnew = (1.f - z) * nn + z * hv;
    hout[t] = hnew;
    p.agg[t] = 0.f;
    if (o == 0) p.sm[n] = 0.f;
    float v0 = hnew * p.attn_w[o], v1 = hnew * p.attn_w[32 + o];
    #pragma unroll
    for (int mm = 16; mm > 0; mm >>= 1) {
        v0 += __shfl_xor(v0, mm, 32);
        v1 += __shfl_xor(v1, mm, 32);
    }
    if (o == 0) { p.ps[n] = v0; p.pd[n] = v1; }
}

// =========================== cooperative kernel ===========================
__launch_bounds__(256, 4)   // VGPR <= 128 -> >= 4 blocks/CU co-resident
__global__ void fused_mpnn(Params p) {
    cg::grid_group grid = cg::this_grid();
    __shared__ float lm[8][32], lh[8][32];
    const int tid = blockIdx.x * 256 + threadIdx.x;
    const int NT  = gridDim.x * 256;
    const int g   = threadIdx.x >> 5;

    for (int t = tid; t < TA; t += NT) phase_setup(p, t);
    grid.sync();

    for (int step = 0; step < 3; ++step) {
        for (int t = tid; t < N_EDGES * 32; t += NT) phase_edge(p, t);
        grid.sync();
        float* hout = (step == 2) ? p.out : p.h;
        for (int t = tid; t < N_NODES * 32; t += NT) phase_gru(p, t, g, lm, lh, hout);
        if (step < 2) grid.sync();
    }
}

// ===================== fallback multi-dispatch kernels =====================
__global__ void setup_kernel(Params p) {
    int t = blockIdx.x * 256 + threadIdx.x;
    if (t < TA) phase_setup(p, t);
}
__launch_bounds__(256)
__global__ void edge_kernel(Params p) {
    int t = blockIdx.x * 256 + threadIdx.x;
    phase_edge(p, t);                                 // grid == N_EDGES*32 exact
}
__launch_bounds__(256)
__global__ void gru_kernel(Params p, float* __restrict__ hout) {
    __shared__ float lm[8][32], lh[8][32];
    int t = blockIdx.x * 256 + threadIdx.x;           // grid == N_NODES*32 exact
    phase_gru(p, t, threadIdx.x >> 5, lm, lh, hout);
}

// ---------------------------------------------------------------------------
extern "C" void kernel_launch(void* const* d_in, const int* in_sizes, int n_in,
                              void* d_out, int out_size, void* d_ws, size_t ws_size,
                              hipStream_t stream) {
    Params p;
    p.node_ids   = (const int*)d_in[0];
    p.edge_ids   = (const int*)d_in[1];
    p.src        = (const int*)d_in[2];
    p.dst        = (const int*)d_in[3];
    p.node_table = (const float*)d_in[4];
    p.edge_table = (const float*)d_in[5];
    p.proj_W     = (const float*)d_in[6];
    p.proj_b     = (const float*)d_in[7];
    p.attn_w     = (const float*)d_in[8];
    p.e1_W1 = (const float*)d_in[9];  p.e1_b1 = (const float*)d_in[10];
    p.e1_W2 = (const float*)d_in[11]; p.e1_b2 = (const float*)d_in[12];
    p.e2_W1 = (const float*)d_in[13]; p.e2_b1 = (const float*)d_in[14];
    p.e2_W2 = (const float*)d_in[15]; p.e2_b2 = (const float*)d_in[16];
    p.gWih  = (const float*)d_in[17]; p.gWhh  = (const float*)d_in[18];
    p.gbih  = (const float*)d_in[19]; p.gbhh  = (const float*)d_in[20];

    // workspace (~4.3 MB): Wq | h | Wpk4 | Wpk2 | ps | pd | agg | sm (contig)
    char* ws = (char*)d_ws;
    p.Wq   = (float*)(ws);                      // 221184
    p.h    = (float*)(ws + 221184);             // 1920000
    p.Wpk4 = (float4*)(ws + 2141184);           // 49152
    p.Wpk2 = (float2*)(ws + 2190336);           // 24576
    p.ps   = (float*)(ws + 2214912);            // 60000
    p.pd   = (float*)(ws + 2274912);            // 60000
    p.agg  = (float*)(ws + 2334912);            // 1920000 (16B aligned)
    p.sm   = (float*)(ws + 4254912);            // 60000 (right after agg)
    p.out  = (float*)d_out;

    // --- cooperative launch with safety margin; deterministic fallback ---
    int maxb = 0, nblk = 512;                   // 512 = r3-proven floor
    if (hipOccupancyMaxActiveBlocksPerMultiprocessor(&maxb, fused_mpnn, 256, 0)
            == hipSuccess && maxb >= 1) {
        if (maxb > 4) maxb = 4;                 // half the theoretical ceiling
        nblk = maxb * 256;
    }
    void* kargs[] = { (void*)&p };
    hipError_t err = hipLaunchCooperativeKernel((void*)fused_mpnn, dim3(nblk),
                                                dim3(256), kargs, 0, stream);
    if (err != hipSuccess) {
        // fallback: r7-style 7-dispatch path (same ws layout, same math)
        setup_kernel<<<(TA + 255) / 256, 256, 0, stream>>>(p);
        for (int step = 0; step < 3; ++step) {
            edge_kernel<<<(N_EDGES * 32) / 256, 256, 0, stream>>>(p);
            float* hout = (step == 2) ? p.out : p.h;
            gru_kernel<<<(N_NODES * 32) / 256, 256, 0, stream>>>(p, hout);
        }
    }
}